// Round 7
// baseline (327.532 us; speedup 1.0000x reference)
//
#include <hip/hip_runtime.h>
#include <math.h>
#include <stdint.h>

#define S_TOK 8192
#define M_DIM 4096
#define NEXP 64
#define CAPACITY 256   // K * ceil(S/E) = 2*128
#define NCHUNK 128     // S / 64
#define KS 16          // split-K slices
#define KSL 256        // slice length (KS*KSL = M_DIM)
#define BT 64          // tokens per tile
#define BK 32          // k per LDS chunk
#define NC (KSL / BK)  // 8 chunks per slice

// ---------------------------------------------------------------------------
// K0: transpose gate weight once: wgT[k][e] = wg[e][k]  (1 MB).
// Gives k_logits a k-major row so B can be fetched as s_load.
// ---------------------------------------------------------------------------
__global__ __launch_bounds__(256) void k_wt(
    const float* __restrict__ wg, float* __restrict__ wgT)
{
    const int k = blockIdx.x * 4 + (threadIdx.x >> 6);
    const int e = threadIdx.x & 63;
    wgT[(size_t)k * NEXP + e] = wg[(size_t)e * M_DIM + k];
}

// ---------------------------------------------------------------------------
// K1: partial logits, split-K. Grid 2048 = 128 token-tiles x 16 k-slices
// = 8 blocks/CU x 4 waves -> 32 waves/CU (v6 was grid-limited at 16).
// B (gate weights) is wave-uniform per k -> SGPR operand via uniform-address
// loads; the FMA is v_fmac v,s,v — zero per-lane B-load instructions.
// A: lane = token; LDS tile [64 tok][32 k] staged via global_load_lds w16
// (linear dest, source k-quad XOR-swizzled by tok&7); each lane reads its
// OWN token's float4 -> 1 ds_read_b128 per 64 FMAs. The 8-way bank sharing
// on that read still covers all 32 banks (8 groups x 4 banks) = full LDS BW;
// the conflict counter is cosmetic (a wave64 b128 read is >=8 cy regardless).
// Wave = 64 tokens x 16 experts (acc[16], brow = 16 SGPRs -> deeper scalar
// prefetch). One barrier per chunk, stage(next) issued before compute(cur).
// LDS 16 KB/block -> 8 blocks/CU fits in 128/160 KB.
// ---------------------------------------------------------------------------
__global__ __launch_bounds__(256) void k_logits(
    const float* __restrict__ x, const float* __restrict__ wgT,
    float* __restrict__ part)
{
    __shared__ float xs[2][BT * BK];   // 8 KB per buffer
    const int tid = threadIdx.x;
    const int tile = blockIdx.x >> 4;      // 0..127
    const int ks   = blockIdx.x & 15;      // 0..15
    const int t0 = tile * BT;
    const int kb = ks * KSL;

    const int lane = tid & 63;
    const int wv = __builtin_amdgcn_readfirstlane(tid >> 6);  // expert group

    auto stage = [&](int buf, int kc) {
        #pragma unroll
        for (int i = 0; i < 2; ++i) {
            const int item = tid + 256 * i;        // 512 items x 16B = 8 KB
            const int tok = item >> 3;             // 0..63
            const int kqp = item & 7;              // phys k-quad slot
            const int kqs = kqp ^ (tok & 7);       // source k-quad (swizzle)
            __builtin_amdgcn_global_load_lds(
                (const __attribute__((address_space(1))) void*)
                    (x + (size_t)(t0 + tok) * M_DIM + kc + 4 * kqs),
                (__attribute__((address_space(3))) void*)(&xs[buf][item * 4]),
                16, 0, 0);
        }
    };

    float acc[16] = {};
    stage(0, kb);
    __syncthreads();

    for (int c = 0; c < NC; ++c) {
        const int buf = c & 1;
        const int kc = kb + c * BK;
        if (c + 1 < NC) stage(buf ^ 1, kc + BK);

        #pragma unroll
        for (int kq = 0; kq < 8; ++kq) {
            const float4 a = *(const float4*)
                &xs[buf][lane * BK + ((kq ^ (lane & 7)) << 2)];
            const float av[4] = {a.x, a.y, a.z, a.w};
            #pragma unroll
            for (int kk = 0; kk < 4; ++kk) {
                // uniform address -> s_load (SGPR B operand)
                const float* brow =
                    wgT + (size_t)(kc + 4 * kq + kk) * NEXP + wv * 16;
                #pragma unroll
                for (int e = 0; e < 16; ++e)
                    acc[e] = fmaf(brow[e], av[kk], acc[e]);
            }
        }
        __syncthreads();
    }

    // store: part[ks][t0+lane][wv*16 .. +16)
    float* dst = part + ((size_t)ks * S_TOK + t0 + lane) * NEXP + wv * 16;
    #pragma unroll
    for (int q = 0; q < 4; ++q) {
        float4 v;
        v.x = acc[4 * q];     v.y = acc[4 * q + 1];
        v.z = acc[4 * q + 2]; v.w = acc[4 * q + 3];
        *(float4*)(dst + 4 * q) = v;
    }
}

// ---------------------------------------------------------------------------
// K2 (fused reduce+rank): 64 tokens per block (8 waves x 8 tokens).
// Reduce partials (deterministic slice order) + softmax + top-2 + me,
// then wave 0 does the per-chunk in-order ranks/histograms via ballots.
// ---------------------------------------------------------------------------
__global__ __launch_bounds__(512) void k_gate(
    const float* __restrict__ part, float* __restrict__ me_g,
    int* __restrict__ idx0_g, int* __restrict__ idx1_g,
    float* __restrict__ gn0_g, float* __restrict__ gn1_g,
    int* __restrict__ rank0_g, int* __restrict__ rank1_g,
    int* __restrict__ cnt_g /* [2][NCHUNK][64] */)
{
    __shared__ float me_sh[NEXP];
    __shared__ int e0_sh[64], e1_sh[64];
    const int tid = threadIdx.x;
    if (tid < NEXP) me_sh[tid] = 0.f;
    __syncthreads();

    const int wv = tid >> 6, lane = tid & 63;
    const int chunk = blockIdx.x;
    float me_acc = 0.f;
    for (int i = 0; i < 8; ++i) {
        const int tt = wv * 8 + i;
        const int t = chunk * 64 + tt;
        float lg = 0.f;
        #pragma unroll
        for (int s = 0; s < KS; ++s)
            lg += part[((size_t)s * S_TOK + t) * NEXP + lane];

        // argmax (lowest index on tie, matching lax.top_k)
        float v = lg; int id = lane;
        #pragma unroll
        for (int off = 32; off > 0; off >>= 1) {
            float v2 = __shfl_xor(v, off);
            int   i2 = __shfl_xor(id, off);
            if (v2 > v || (v2 == v && i2 < id)) { v = v2; id = i2; }
        }
        const float mx = v; const int i0 = id;

        const float p = expf(lg - mx);
        float sum = p;
        #pragma unroll
        for (int off = 32; off > 0; off >>= 1) sum += __shfl_xor(sum, off);
        me_acc += p / sum;

        // second argmax, excluding i0
        float v1 = (lane == i0) ? -INFINITY : lg; int id1 = lane;
        #pragma unroll
        for (int off = 32; off > 0; off >>= 1) {
            float v2 = __shfl_xor(v1, off);
            int   i2 = __shfl_xor(id1, off);
            if (v2 > v1 || (v2 == v1 && i2 < id1)) { v1 = v2; id1 = i2; }
        }

        const float g0 = 1.0f / sum;
        const float g1 = expf(v1 - mx) / sum;
        const float den = fmaxf(g0 + g1, 1.1920929e-07f);
        if (lane == 0) {
            idx0_g[t] = i0;
            idx1_g[t] = id1;
            gn0_g[t] = g0 / den;
            gn1_g[t] = g1 / den;
            e0_sh[tt] = i0;
            e1_sh[tt] = id1;
        }
    }
    atomicAdd(&me_sh[lane], me_acc);
    __syncthreads();
    if (tid < NEXP) atomicAdd(&me_g[tid], me_sh[tid]);

    // rank phase: wave 0, lane = token within chunk
    if (wv == 0) {
        const int s = chunk * 64 + lane;
        const int e0 = e0_sh[lane], e1 = e1_sh[lane];
        const unsigned long long lt = (1ull << lane) - 1ull;
        int r0 = 0, r1 = 0, c0 = 0, c1 = 0;
        #pragma unroll
        for (int e = 0; e < 64; ++e) {
            unsigned long long m0 = __ballot(e0 == e);
            unsigned long long m1 = __ballot(e1 == e);
            if (e0 == e) r0 = __popcll(m0 & lt);
            if (e1 == e) r1 = __popcll(m1 & lt);
            if (lane == e) { c0 = __popcll(m0); c1 = __popcll(m1); }
        }
        rank0_g[s] = r0;
        rank1_g[s] = r1;
        cnt_g[chunk * 64 + lane] = c0;
        cnt_g[NCHUNK * 64 + chunk * 64 + lane] = c1;
    }
}

// ---------------------------------------------------------------------------
// K3: parallel scan — one wave per (k,e), shfl prefix over 128 chunks.
// Also emits ce (tot0) and the load-balance loss.
// ---------------------------------------------------------------------------
__global__ __launch_bounds__(256) void k_scan(
    const int* __restrict__ cnt_g, int* __restrict__ base_g,
    int* __restrict__ tot0_g, const float* __restrict__ me_g,
    float* __restrict__ loss_out)
{
    const int wv = threadIdx.x >> 6, lane = threadIdx.x & 63;
    const int g = blockIdx.x * 4 + wv;         // 0..127
    const int k = g >> 6, e = g & 63;

    const int c0 = cnt_g[(k * NCHUNK + 2 * lane)     * 64 + e];
    const int c1 = cnt_g[(k * NCHUNK + 2 * lane + 1) * 64 + e];
    const int s = c0 + c1;
    int incl = s;
    #pragma unroll
    for (int d = 1; d < 64; d <<= 1) {
        int v = __shfl_up(incl, d);
        if (lane >= d) incl += v;
    }
    const int excl = incl - s;
    base_g[(k * NCHUNK + 2 * lane)     * 64 + e] = excl;
    base_g[(k * NCHUNK + 2 * lane + 1) * 64 + e] = excl + c0;
    const int total = __shfl(incl, 63);
    if (k == 0 && lane == 0) {
        tot0_g[e] = total;
        atomicAdd(loss_out, me_g[e] * (float)total * 9.5367431640625e-07f); // E/S^2
    }
}

// ---------------------------------------------------------------------------
// K4 (fused weight+out): per-token combine weight (capacity check) computed
// block-uniformly (L1 broadcast loads), then out[s,:] = w * x[s,:].
// ---------------------------------------------------------------------------
__global__ __launch_bounds__(256) void k_out(
    const float* __restrict__ x,
    const int* __restrict__ idx0_g, const int* __restrict__ idx1_g,
    const float* __restrict__ gn0_g, const float* __restrict__ gn1_g,
    const int* __restrict__ rank0_g, const int* __restrict__ rank1_g,
    const int* __restrict__ base_g, const int* __restrict__ tot0_g,
    float* __restrict__ out)
{
    const int s = blockIdx.x;
    const int chunk = s >> 6;
    const int e0 = idx0_g[s], e1 = idx1_g[s];
    const int loc0 = base_g[chunk * 64 + e0] + rank0_g[s];
    const int loc1 = base_g[(NCHUNK + chunk) * 64 + e1] + rank1_g[s] + tot0_g[e1];
    float w = 0.f;
    if (loc0 < CAPACITY) w += gn0_g[s];
    if (loc1 < CAPACITY) w += gn1_g[s];

    const float4* xr = (const float4*)(x + (size_t)s * M_DIM);
    float4* o = (float4*)(out + (size_t)s * M_DIM);
    #pragma unroll
    for (int i = 0; i < 4; ++i) {
        float4 v = xr[threadIdx.x + 256 * i];
        v.x *= w; v.y *= w; v.z *= w; v.w *= w;
        o[threadIdx.x + 256 * i] = v;
    }
}

// ---------------------------------------------------------------------------
extern "C" void kernel_launch(void* const* d_in, const int* in_sizes, int n_in,
                              void* d_out, int out_size, void* d_ws, size_t ws_size,
                              hipStream_t stream)
{
    const float* x  = (const float*)d_in[0];
    const float* wg = (const float*)d_in[1];
    float* out = (float*)d_out;
    float* loss = out + (size_t)S_TOK * M_DIM;

    // ws layout (floats/ints, 4B):
    float* part = (float*)d_ws;                         // [KS][S][E] = 33.55 MB
    float* me   = part + (size_t)KS * S_TOK * NEXP;     // [64]
    int*  idx0  = (int*)(me + NEXP);                    // [S]
    int*  idx1  = idx0 + S_TOK;                         // [S]
    float* gn0  = (float*)(idx1 + S_TOK);               // [S]
    float* gn1  = gn0 + S_TOK;                          // [S]
    int*  rank0 = (int*)(gn1 + S_TOK);                  // [S]
    int*  rank1 = rank0 + S_TOK;                        // [S]
    int*  cnt   = rank1 + S_TOK;                        // [2][128][64]
    int*  base  = cnt + 2 * NCHUNK * 64;                // [2][128][64]
    int*  tot0  = base + 2 * NCHUNK * 64;               // [64]
    float* wgT  = (float*)(tot0 + NEXP);                // [M][E] = 1 MB

    hipMemsetAsync(me, 0, NEXP * sizeof(float), stream);
    hipMemsetAsync(loss, 0, sizeof(float), stream);

    k_wt<<<M_DIM / 4, 256, 0, stream>>>(wg, wgT);
    k_logits<<<(S_TOK / BT) * KS, 256, 0, stream>>>(x, wgT, part);
    k_gate<<<NCHUNK, 512, 0, stream>>>(part, me, idx0, idx1, gn0, gn1,
                                       rank0, rank1, cnt);
    k_scan<<<32, 256, 0, stream>>>(cnt, base, tot0, me, loss);
    k_out<<<S_TOK, 256, 0, stream>>>(x, idx0, idx1, gn0, gn1,
                                     rank0, rank1, base, tot0, out);
}